// Round 17
// baseline (378.808 us; speedup 1.0000x reference)
//
#include <hip/hip_runtime.h>
#include <math.h>

#define NN 50000
#define EE 400000
#define ETOT 450000      // EE + NN self loops
#define CC 64
#define HH 4
#define DEA 16
#define NBATCH 64
#define HC 256           // HH*CC
#define EPSV 1e-5f
#define NB 49            // ceil(NN/1024)
#define NGB 782          // ceil(NN/64)
#define NPW 2            // nodes per wave in k_gat
#define HISTB 1758       // ceil(ETOT/256)
#define PACKB 128        // 32768 pack threads / 256
#define STATB 196        // ceil(NN/256)

typedef unsigned short ushort_t;
typedef unsigned int uint_t;
using h2t = decltype(__builtin_amdgcn_cvt_pkrtz(0.0f, 0.0f));

__device__ __forceinline__ float4 ld4(const float* p){ return *(const float4*)p; }
__device__ __forceinline__ int rfl(int v){ return __builtin_amdgcn_readfirstlane(v); }
__device__ __forceinline__ ushort_t f2b(float f){
  uint_t u = __float_as_uint(f);
  uint_t r = (u + 0x7FFFu + ((u >> 16) & 1u)) >> 16;
  return (ushort_t)r;
}
__device__ __forceinline__ float b2f_lo(uint_t u){ return __uint_as_float(u << 16); }
__device__ __forceinline__ float b2f_hi(uint_t u){ return __uint_as_float(u & 0xFFFF0000u); }
__device__ __forceinline__ uint_t h2u(h2t h){ return __builtin_bit_cast(uint_t, h); }
__device__ __forceinline__ h2t u2h(uint_t u){ return __builtin_bit_cast(h2t, u); }

// DPP-based sum over aligned 16-lane groups (R11-verified).
template<int CTRL>
__device__ __forceinline__ float dpp_add(float x){
  int y = __builtin_amdgcn_update_dpp(0, __float_as_int(x), CTRL, 0xF, 0xF, true);
  return x + __int_as_float(y);
}
__device__ __forceinline__ float red16(float x){
  x = dpp_add<0xB1>(x);    // quad_perm xor1
  x = dpp_add<0x4E>(x);    // quad_perm xor2
  x = dpp_add<0x141>(x);   // row_half_mirror
  x = dpp_add<0x140>(x);   // row_mirror
  return x;
}

// ---------- k_pre1: edge_attr column sums (blocks < 1024) + dst histogram ----------
__global__ __launch_bounds__(256)
void k_pre1(const float* __restrict__ ea, const int* __restrict__ dst,
            float* __restrict__ easum, int* __restrict__ cnt){
  int tid = threadIdx.x;
  int bid = blockIdx.x;
  int e = bid*256 + tid;
  if (e < ETOT){
    int d = (e < EE) ? dst[e] : (e - EE);
    atomicAdd(&cnt[d], 1);
  }
  if (bid < 1024){
    int gid = bid*256 + tid;
    const int gsz = 262144;            // multiple of 16 -> column-stable
    float s = 0.f;
    for (long long i = gid; i < (long long)EE*DEA; i += gsz) s += ea[i];
    __shared__ float sd[256];
    sd[tid] = s; __syncthreads();
    if (tid < DEA){
      float t = 0.f;
      for (int j = tid; j < 256; j += DEA) t += sd[j];
      atomicAdd(&easum[tid], t);
    }
  }
}

// ---------- CSR scans ----------
__global__ __launch_bounds__(1024)
void k_scan1(const int* __restrict__ cnt, int* __restrict__ loc, int* __restrict__ bsum){
  __shared__ int wsum[16];
  int tid = threadIdx.x, lane = tid & 63, wv = tid >> 6;
  int i = blockIdx.x*1024 + tid;
  int v = (i < NN) ? cnt[i] : 0;
  int incl = v;
  #pragma unroll
  for (int off = 1; off < 64; off <<= 1){
    int t = __shfl_up(incl, off, 64);
    if (lane >= off) incl += t;
  }
  if (lane == 63) wsum[wv] = incl;
  __syncthreads();
  if (wv == 0){
    int s = (lane < 16) ? wsum[lane] : 0;
    #pragma unroll
    for (int off = 1; off < 16; off <<= 1){
      int t = __shfl_up(s, off, 64);
      if (lane >= off) s += t;
    }
    if (lane < 16) wsum[lane] = s;
  }
  __syncthreads();
  int excl = (wv ? wsum[wv-1] : 0) + incl - v;
  if (i < NN) loc[i] = excl;
  if (tid == 1023) bsum[blockIdx.x] = wsum[15];
}

__global__ void k_scan2(int* __restrict__ bsum, int* __restrict__ row_ptr){
  int lane = threadIdx.x;   // 64 threads
  int v = (lane < NB) ? bsum[lane] : 0;
  int incl = v;
  #pragma unroll
  for (int off = 1; off < 64; off <<= 1){
    int t = __shfl_up(incl, off, 64);
    if (lane >= off) incl += t;
  }
  if (lane < NB) bsum[lane] = incl - v;
  if (lane == 63) row_ptr[NN] = incl;
}

__global__ __launch_bounds__(1024)
void k_scan3(const int* __restrict__ loc, const int* __restrict__ bsum,
             int* __restrict__ row_ptr, int* __restrict__ wp){
  int i = blockIdx.x*1024 + threadIdx.x;
  if (i < NN){
    int v = loc[i] + bsum[blockIdx.x];
    row_ptr[i] = v; wp[i] = v;
  }
}

// ---------- k_pre2: scatter + pack W (f16 pairs) + layer-0 GraphNorm stats ----------
__global__ __launch_bounds__(256)
void k_pre2(const int* __restrict__ dst, const int* __restrict__ src,
            const float* __restrict__ ea, const float* __restrict__ easum,
            int* __restrict__ wp, int* __restrict__ csrc, uint_t* __restrict__ eas,
            const float* __restrict__ Wl, const float* __restrict__ Wr,
            uint_t* __restrict__ Wq,
            const float* __restrict__ x, const int* __restrict__ batch,
            float* __restrict__ S, float* __restrict__ Q){
  int bid = blockIdx.x;
  int tid = threadIdx.x;
  if (bid < HISTB){
    int e = bid*256 + tid;
    if (e >= ETOT) return;
    int d, s;
    if (e < EE){ d = dst[e]; s = src[e]; } else { d = e - EE; s = d; }
    int pos = atomicAdd(&wp[d], 1);
    csrc[pos] = s;
    float buf[16];
    if (e < EE){
      #pragma unroll
      for (int q = 0; q < 4; q++){
        float4 v = ld4(ea + (size_t)e*DEA + q*4);
        buf[q*4+0]=v.x; buf[q*4+1]=v.y; buf[q*4+2]=v.z; buf[q*4+3]=v.w;
      }
    } else {
      const float invE = 1.0f / (float)EE;
      #pragma unroll
      for (int k = 0; k < 16; k++) buf[k] = easum[k]*invE;
    }
    uint_t pk[8];
    #pragma unroll
    for (int p = 0; p < 8; p++)
      pk[p] = h2u(__builtin_amdgcn_cvt_pkrtz(buf[2*p], buf[2*p+1]));
    *(uint4*)(eas + (size_t)pos*8 + 0) = make_uint4(pk[0], pk[1], pk[2], pk[3]);
    *(uint4*)(eas + (size_t)pos*8 + 4) = make_uint4(pk[4], pk[5], pk[6], pk[7]);
  } else if (bid < HISTB + PACKB){
    int t = (bid - HISTB)*256 + tid;   // < 32768
    int col = t & 255;
    int kp  = (t >> 8) & 31;
    int lm  = t >> 13;                 // layer*2 + mat
    int l = lm >> 1, mat = lm & 1;
    const float* W = (mat ? Wr : Wl) + (size_t)l*CC*HC;
    float w0 = W[(size_t)(2*kp+0)*HC + col];
    float w1 = W[(size_t)(2*kp+1)*HC + col];
    Wq[(size_t)lm*8192 + kp*256 + col] = h2u(__builtin_amdgcn_cvt_pkrtz(w0, w1));
  } else {
    int c = tid & 63, g = tid >> 6;
    int r0 = (bid - HISTB - PACKB)*256;
    int hiR = r0 + 256; if (hiR > NN) hiR = NN;
    float s = 0.f, q = 0.f;
    int curb = -1;
    for (int n = r0 + g; n < hiR; n += 4){
      int b = batch[n];
      if (b != curb){
        if (curb >= 0){ atomicAdd(&S[curb*64+c], s); atomicAdd(&Q[curb*64+c], q); }
        curb = b; s = 0.f; q = 0.f;
      }
      float v = x[(size_t)n*CC + c];
      s += v; q += v*v;
    }
    if (curb >= 0){ atomicAdd(&S[curb*64+c], s); atomicAdd(&Q[curb*64+c], q); }
  }
}

// ---------- GraphNorm stats (layer 1 only) ----------
__global__ __launch_bounds__(256)
void k_stats(const float* __restrict__ x, const int* __restrict__ batch,
             float* __restrict__ S, float* __restrict__ Q){
  int c = threadIdx.x & 63, g = threadIdx.x >> 6;
  int r0 = blockIdx.x*256;
  int hiR = r0 + 256; if (hiR > NN) hiR = NN;
  float s = 0.f, q = 0.f;
  int curb = -1;
  for (int n = r0 + g; n < hiR; n += 4){
    int b = batch[n];
    if (b != curb){
      if (curb >= 0){ atomicAdd(&S[curb*64+c], s); atomicAdd(&Q[curb*64+c], q); }
      curb = b; s = 0.f; q = 0.f;
    }
    float v = x[(size_t)n*CC + c];
    s += v; q += v*v;
  }
  if (curb >= 0){ atomicAdd(&S[curb*64+c], s); atomicAdd(&Q[curb*64+c], q); }
}

__device__ __forceinline__ int lowerb(const int* a, int n, int key){
  int lo = 0, hi = n;
  while (lo < hi){ int mid = (lo+hi) >> 1; if (a[mid] < key) lo = mid+1; else hi = mid; }
  return lo;
}

// ---------- fold stats to per-(batch,channel) scale/shift ----------
__global__ void k_fin(const float* __restrict__ S, const float* __restrict__ Q,
                      const int* __restrict__ batch,
                      const float* __restrict__ w, const float* __restrict__ bb,
                      const float* __restrict__ ms,
                      float* __restrict__ scale, float* __restrict__ shift){
  __shared__ float cntf;
  int b = blockIdx.x, c = threadIdx.x;   // 64 x 64
  if (c == 0){
    int lo = lowerb(batch, NN, b), hi = lowerb(batch, NN, b+1);
    cntf = fmaxf((float)(hi - lo), 1.f);
  }
  __syncthreads();
  float inv = 1.f / cntf;
  float m = S[b*64+c] * inv;
  float a = ms[c] * m;
  float var = Q[b*64+c]*inv - 2.f*a*m + a*a;   // E[(x-a)^2]
  var = fmaxf(var, 0.f);
  float rstd = rsqrtf(var + EPSV);
  float sc = rstd * w[c];
  scale[b*64+c] = sc;
  shift[b*64+c] = bb[c] - a*sc;
}

// ---------- GEMM (f16 dot2) with fused GraphNorm+ReLU: [N,64] @ [64,256] -> bf16 ----------
__global__ __launch_bounds__(256)
void k_gemm(const float* __restrict__ x, const int* __restrict__ batch,
            const float* __restrict__ scale, const float* __restrict__ shift,
            const uint_t* __restrict__ WqA, const uint_t* __restrict__ WqB,
            ushort_t* __restrict__ outA, ushort_t* __restrict__ outB){
  const uint_t* Wq = blockIdx.z ? WqB : WqA;
  ushort_t* out = blockIdx.z ? outB : outA;
  int n0 = blockIdx.x * 64;
  __shared__ uint_t hTp[32][72];    // [kp][row] f16 pairs, 9 KB
  int tid = threadIdx.x;
  for (int t = tid; t < 1024; t += 256){      // 64 rows x 16 float4
    int r = t >> 4, ch = t & 15;
    int n = n0 + r;
    float4 v = make_float4(0.f,0.f,0.f,0.f);
    if (n < NN){
      int b = batch[n];
      v = ld4(x + (size_t)n*CC + ch*4);
      float4 sc = ld4(scale + b*64 + ch*4);
      float4 sh = ld4(shift + b*64 + ch*4);
      v.x = fmaxf(v.x*sc.x + sh.x, 0.f);
      v.y = fmaxf(v.y*sc.y + sh.y, 0.f);
      v.z = fmaxf(v.z*sc.z + sh.z, 0.f);
      v.w = fmaxf(v.w*sc.w + sh.w, 0.f);
    }
    hTp[ch*2+0][r] = h2u(__builtin_amdgcn_cvt_pkrtz(v.x, v.y));
    hTp[ch*2+1][r] = h2u(__builtin_amdgcn_cvt_pkrtz(v.z, v.w));
  }
  __syncthreads();
  int c = tid & 63, rg = tid >> 6;
  int r0 = rg * 16;
  float acc[16][4];
  #pragma unroll
  for (int i = 0; i < 16; i++){ acc[i][0]=0.f; acc[i][1]=0.f; acc[i][2]=0.f; acc[i][3]=0.f; }
  #pragma unroll 4
  for (int kp = 0; kp < 32; kp++){
    uint4 a0 = *(const uint4*)&hTp[kp][r0+0];
    uint4 a1 = *(const uint4*)&hTp[kp][r0+4];
    uint4 a2 = *(const uint4*)&hTp[kp][r0+8];
    uint4 a3 = *(const uint4*)&hTp[kp][r0+12];
    uint4 wv = *(const uint4*)(Wq + (size_t)kp*256 + c*4);
    h2t w0 = u2h(wv.x), w1 = u2h(wv.y), w2 = u2h(wv.z), w3 = u2h(wv.w);
    const uint_t av[16] = {a0.x,a0.y,a0.z,a0.w, a1.x,a1.y,a1.z,a1.w,
                           a2.x,a2.y,a2.z,a2.w, a3.x,a3.y,a3.z,a3.w};
    #pragma unroll
    for (int i = 0; i < 16; i++){
      h2t e = u2h(av[i]);
      acc[i][0] = __builtin_amdgcn_fdot2(e, w0, acc[i][0], false);
      acc[i][1] = __builtin_amdgcn_fdot2(e, w1, acc[i][1], false);
      acc[i][2] = __builtin_amdgcn_fdot2(e, w2, acc[i][2], false);
      acc[i][3] = __builtin_amdgcn_fdot2(e, w3, acc[i][3], false);
    }
  }
  #pragma unroll
  for (int i = 0; i < 16; i++){
    int n = n0 + r0 + i;
    if (n < NN){
      uint2 o;
      o.x = (uint_t)f2b(acc[i][0]) | ((uint_t)f2b(acc[i][1]) << 16);
      o.y = (uint_t)f2b(acc[i][2]) | ((uint_t)f2b(acc[i][3]) << 16);
      *(uint2*)(out + (size_t)n*HC + c*4) = o;
    }
  }
}

// ---------- FUSED GATv2: two-edge batched online softmax, NO explicit prefetch ----------
// A/B vs R16: direct in-loop loads (compiler hoists within iteration); at 74% VALUBusy
// and ~3.3 waves/SIMD the pair's ~700cy VALU work covers gather latency, so the
// prefetch clamp/rotate machinery (~20 instr/pair) is removed.
__global__ __launch_bounds__(256, 4)
void k_gat(const int* __restrict__ row_ptr, const int* __restrict__ csrc,
           const uint_t* __restrict__ eas,
           const ushort_t* __restrict__ xlh, const ushort_t* __restrict__ xrh,
           const float* __restrict__ We, const float* __restrict__ att,
           const float* __restrict__ bias, const float* __restrict__ resid,
           float* __restrict__ out){
  int lane = threadIdx.x & 63;
  int h = lane >> 4, cg = lane & 15;
  int col = h*64 + cg*4;
  int wid = (blockIdx.x*256 + threadIdx.x) >> 6;
  int n0 = wid * NPW;
  if (n0 >= NN) return;
  int n1 = n0 + NPW; if (n1 > NN) n1 = NN;

  uint_t werh[4][8];
  #pragma unroll
  for (int p = 0; p < 8; p++){
    float4 w0 = ld4(We + (size_t)(2*p+0)*HC + col);
    float4 w1 = ld4(We + (size_t)(2*p+1)*HC + col);
    werh[0][p] = h2u(__builtin_amdgcn_cvt_pkrtz(w0.x, w1.x));
    werh[1][p] = h2u(__builtin_amdgcn_cvt_pkrtz(w0.y, w1.y));
    werh[2][p] = h2u(__builtin_amdgcn_cvt_pkrtz(w0.z, w1.z));
    werh[3][p] = h2u(__builtin_amdgcn_cvt_pkrtz(w0.w, w1.w));
  }
  #pragma unroll
  for (int j = 0; j < 4; j++)
    #pragma unroll
    for (int p = 0; p < 8; p++)
      asm volatile("" : "+v"(werh[j][p]));   // pin: no per-edge remat

  float4 attv = ld4(att + col);
  float4 biasv = ld4(bias + cg*4);

  for (int n = n0; n < n1; n++){
    int rr0 = rfl(row_ptr[n]), rr1 = rfl(row_ptr[n+1]);
    uint2 xrp = *(const uint2*)(xrh + (size_t)n*HC + col);
    float xr0 = b2f_lo(xrp.x), xr1 = b2f_hi(xrp.x);
    float xr2 = b2f_lo(xrp.y), xr3 = b2f_hi(xrp.y);
    float m = -3.4e38f, dsum = 0.f;
    float a0 = 0.f, a1 = 0.f, a2 = 0.f, a3 = 0.f;

    for (int idx = rr0; idx < rr1; idx += 2){
      int i1c = (idx+1 < rr1) ? idx+1 : idx;    // tail: clamp to same edge
      int sA = rfl(csrc[idx]);
      int sB = rfl(csrc[i1c]);
      uint2 xA = *(const uint2*)(xlh + (size_t)sA*HC + col);
      uint2 xB = *(const uint2*)(xlh + (size_t)sB*HC + col);
      uint_t eaA[8], eaB[8];
      {
        const uint_t* p0 = eas + (size_t)idx*8;
        const uint_t* p1 = eas + (size_t)i1c*8;
        #pragma unroll
        for (int p = 0; p < 8; p++){ eaA[p] = p0[p]; eaB[p] = p1[p]; }
      }

      // unpack both xl rows
      float xl00 = b2f_lo(xA.x), xl01 = b2f_hi(xA.x);
      float xl02 = b2f_lo(xA.y), xl03 = b2f_hi(xA.y);
      float xl10 = b2f_lo(xB.x), xl11 = b2f_hi(xB.x);
      float xl12 = b2f_lo(xB.y), xl13 = b2f_hi(xB.y);

      // two independent edge-attr dots
      float p00=0.f,p01=0.f,p02=0.f,p03=0.f, p10=0.f,p11=0.f,p12=0.f,p13=0.f;
      #pragma unroll
      for (int p = 0; p < 8; p++){
        h2t e0 = u2h(eaA[p]);
        h2t e1 = u2h(eaB[p]);
        p00 = __builtin_amdgcn_fdot2(e0, u2h(werh[0][p]), p00, false);
        p10 = __builtin_amdgcn_fdot2(e1, u2h(werh[0][p]), p10, false);
        p01 = __builtin_amdgcn_fdot2(e0, u2h(werh[1][p]), p01, false);
        p11 = __builtin_amdgcn_fdot2(e1, u2h(werh[1][p]), p11, false);
        p02 = __builtin_amdgcn_fdot2(e0, u2h(werh[2][p]), p02, false);
        p12 = __builtin_amdgcn_fdot2(e1, u2h(werh[2][p]), p12, false);
        p03 = __builtin_amdgcn_fdot2(e0, u2h(werh[3][p]), p03, false);
        p13 = __builtin_amdgcn_fdot2(e1, u2h(werh[3][p]), p13, false);
      }
      float u00 = xl00 + xr0 + p00; u00 = (u00 > 0.f) ? u00 : 0.2f*u00;
      float u01 = xl01 + xr1 + p01; u01 = (u01 > 0.f) ? u01 : 0.2f*u01;
      float u02 = xl02 + xr2 + p02; u02 = (u02 > 0.f) ? u02 : 0.2f*u02;
      float u03 = xl03 + xr3 + p03; u03 = (u03 > 0.f) ? u03 : 0.2f*u03;
      float u10 = xl10 + xr0 + p10; u10 = (u10 > 0.f) ? u10 : 0.2f*u10;
      float u11 = xl11 + xr1 + p11; u11 = (u11 > 0.f) ? u11 : 0.2f*u11;
      float u12 = xl12 + xr2 + p12; u12 = (u12 > 0.f) ? u12 : 0.2f*u12;
      float u13 = xl13 + xr3 + p13; u13 = (u13 > 0.f) ? u13 : 0.2f*u13;
      float pl0 = u00*attv.x + u01*attv.y + u02*attv.z + u03*attv.w;
      float pl1 = u10*attv.x + u11*attv.y + u12*attv.z + u13*attv.w;
      pl0 = red16(pl0);
      pl1 = red16(pl1);
      if (idx + 1 >= rr1) pl1 = -3.4e38f;   // odd tail: w1 -> 0

      // combined two-edge online softmax update
      float mn = fmaxf(fmaxf(m, pl0), pl1);     // v_max3
      float sc = __expf(m - mn);
      float w0 = __expf(pl0 - mn);
      float w1 = __expf(pl1 - mn);
      dsum = dsum*sc + w0 + w1;
      a0 = a0*sc + w0*xl00 + w1*xl10;
      a1 = a1*sc + w0*xl01 + w1*xl11;
      a2 = a2*sc + w0*xl02 + w1*xl12;
      a3 = a3*sc + w0*xl03 + w1*xl13;
      m = mn;
    }

    float inv = 1.0f / dsum;
    float o0 = a0*inv, o1 = a1*inv, o2 = a2*inv, o3 = a3*inv;
    #pragma unroll
    for (int off = 16; off < 64; off <<= 1){
      o0 += __shfl_xor(o0, off, 64);
      o1 += __shfl_xor(o1, off, 64);
      o2 += __shfl_xor(o2, off, 64);
      o3 += __shfl_xor(o3, off, 64);
    }
    if (lane < 16){
      float r0v = o0*0.25f + biasv.x;
      float r1v = o1*0.25f + biasv.y;
      float r2v = o2*0.25f + biasv.z;
      float r3v = o3*0.25f + biasv.w;
      if (resid){
        float4 rv = ld4(resid + (size_t)n*CC + cg*4);
        r0v += rv.x; r1v += rv.y; r2v += rv.z; r3v += rv.w;
      }
      *(float4*)(out + (size_t)n*CC + cg*4) = make_float4(r0v, r1v, r2v, r3v);
    }
  }
}

extern "C" void kernel_launch(void* const* d_in, const int* in_sizes, int n_in,
                              void* d_out, int out_size, void* d_ws, size_t ws_size,
                              hipStream_t stream) {
  const float* x     = (const float*)d_in[0];
  const int*   ei    = (const int*)d_in[1];
  const int*   src   = ei;
  const int*   dst   = ei + EE;
  const float* ea    = (const float*)d_in[2];
  const int*   batch = (const int*)d_in[3];
  const float* Wl    = (const float*)d_in[4];
  const float* Wr    = (const float*)d_in[5];
  const float* We    = (const float*)d_in[6];
  const float* att   = (const float*)d_in[7];
  const float* gb    = (const float*)d_in[8];
  const float* gw    = (const float*)d_in[9];
  const float* gnb   = (const float*)d_in[10];
  const float* gms   = (const float*)d_in[11];
  float* out = (float*)d_out;

  char* ws = (char*)d_ws;
  size_t off = 0;
  auto alloc = [&](size_t bytes) -> void* {
    void* p = ws + off; off += (bytes + 255) & ~(size_t)255; return p;
  };
  // zero-init region first (single memset covers cnt + easum + statSQ)
  int*   cnt     = (int*)alloc(NN*sizeof(int));
  float* easum   = (float*)alloc(64*sizeof(float));
  float* statSQ  = (float*)alloc(4*4096*sizeof(float));   // S0,S1,Q0,Q1
  size_t zbytes  = off;
  int*   loc     = (int*)alloc(NN*sizeof(int));
  int*   bsum    = (int*)alloc(64*sizeof(int));
  int*   wp      = (int*)alloc(NN*sizeof(int));
  int*   row_ptr = (int*)alloc((NN+1)*sizeof(int));
  int*   csrc    = (int*)alloc((size_t)ETOT*sizeof(int));
  uint_t* eas    = (uint_t*)alloc((size_t)ETOT*8*sizeof(uint_t));   // f16-packed
  float* scaleb  = (float*)alloc(4096*sizeof(float));
  float* shiftb  = (float*)alloc(4096*sizeof(float));
  uint_t* Wq     = (uint_t*)alloc((size_t)4*8192*sizeof(uint_t));   // f16-pair weights
  ushort_t* xlh  = (ushort_t*)alloc((size_t)NN*HC*sizeof(ushort_t));
  ushort_t* xrh  = (ushort_t*)alloc((size_t)NN*HC*sizeof(ushort_t));
  float* xbuf    = (float*)alloc((size_t)NN*CC*sizeof(float));
  if (off > ws_size) return;   // insufficient workspace -> fail loudly (no launch)

  hipMemsetAsync(cnt, 0, zbytes, stream);
  k_pre1<<<HISTB, 256, 0, stream>>>(ea, dst, easum, cnt);
  k_scan1<<<NB, 1024, 0, stream>>>(cnt, loc, bsum);
  k_scan2<<<1, 64, 0, stream>>>(bsum, row_ptr);
  k_scan3<<<NB, 1024, 0, stream>>>(loc, bsum, row_ptr, wp);
  k_pre2<<<HISTB + PACKB + STATB, 256, 0, stream>>>(dst, src, ea, easum, wp, csrc, eas,
                                                    Wl, Wr, Wq, x, batch,
                                                    statSQ + 0, statSQ + 2*4096);

  int gatBlocks = (NN + NPW*4 - 1) / (NPW*4);
  for (int i = 0; i < 2; i++){
    const float* xin = i ? xbuf : x;
    float* S = statSQ + i*4096;
    float* Q = statSQ + 2*4096 + i*4096;
    if (i) k_stats<<<(NN+255)/256, 256, 0, stream>>>(xin, batch, S, Q);
    k_fin<<<64, 64, 0, stream>>>(S, Q, batch, gw + i*CC, gnb + i*CC, gms + i*CC, scaleb, shiftb);
    k_gemm<<<dim3(NGB, 1, 2), 256, 0, stream>>>(xin, batch, scaleb, shiftb,
                                                Wq + (size_t)(i*2+0)*8192,
                                                Wq + (size_t)(i*2+1)*8192,
                                                xlh, xrh);
    k_gat<<<gatBlocks, 256, 0, stream>>>(row_ptr, csrc, eas, xlh, xrh,
                                         We + (size_t)i*DEA*HC, att + i*HH*CC,
                                         gb + i*CC, i ? x : nullptr, i ? out : xbuf);
  }
}

// Round 18
// 373.224 us; speedup vs baseline: 1.0150x; 1.0150x over previous
//
#include <hip/hip_runtime.h>
#include <math.h>

#define NN 50000
#define EE 400000
#define ETOT 450000      // EE + NN self loops
#define CC 64
#define HH 4
#define DEA 16
#define NBATCH 64
#define HC 256           // HH*CC
#define EPSV 1e-5f
#define NB 49            // ceil(NN/1024)
#define NGB 782          // ceil(NN/64)
#define NPW 2            // nodes per wave in k_gat
#define HISTB 1758       // ceil(ETOT/256)
#define PACKB 128        // 32768 pack threads / 256
#define STATB 196        // ceil(NN/256)

typedef unsigned short ushort_t;
typedef unsigned int uint_t;
using h2t = decltype(__builtin_amdgcn_cvt_pkrtz(0.0f, 0.0f));

__device__ __forceinline__ float4 ld4(const float* p){ return *(const float4*)p; }
__device__ __forceinline__ int rfl(int v){ return __builtin_amdgcn_readfirstlane(v); }
__device__ __forceinline__ ushort_t f2b(float f){
  uint_t u = __float_as_uint(f);
  uint_t r = (u + 0x7FFFu + ((u >> 16) & 1u)) >> 16;
  return (ushort_t)r;
}
__device__ __forceinline__ float b2f_lo(uint_t u){ return __uint_as_float(u << 16); }
__device__ __forceinline__ float b2f_hi(uint_t u){ return __uint_as_float(u & 0xFFFF0000u); }
__device__ __forceinline__ uint_t h2u(h2t h){ return __builtin_bit_cast(uint_t, h); }
__device__ __forceinline__ h2t u2h(uint_t u){ return __builtin_bit_cast(h2t, u); }

// DPP-based sum over aligned 16-lane groups (R11-verified).
template<int CTRL>
__device__ __forceinline__ float dpp_add(float x){
  int y = __builtin_amdgcn_update_dpp(0, __float_as_int(x), CTRL, 0xF, 0xF, true);
  return x + __int_as_float(y);
}
__device__ __forceinline__ float red16(float x){
  x = dpp_add<0xB1>(x);    // quad_perm xor1
  x = dpp_add<0x4E>(x);    // quad_perm xor2
  x = dpp_add<0x141>(x);   // row_half_mirror
  x = dpp_add<0x140>(x);   // row_mirror
  return x;
}

// ---------- k_pre1: edge_attr column sums (blocks < 1024) + dst histogram ----------
__global__ __launch_bounds__(256)
void k_pre1(const float* __restrict__ ea, const int* __restrict__ dst,
            float* __restrict__ easum, int* __restrict__ cnt){
  int tid = threadIdx.x;
  int bid = blockIdx.x;
  int e = bid*256 + tid;
  if (e < ETOT){
    int d = (e < EE) ? dst[e] : (e - EE);
    atomicAdd(&cnt[d], 1);
  }
  if (bid < 1024){
    int gid = bid*256 + tid;
    const int gsz = 262144;            // multiple of 16 -> column-stable
    float s = 0.f;
    for (long long i = gid; i < (long long)EE*DEA; i += gsz) s += ea[i];
    __shared__ float sd[256];
    sd[tid] = s; __syncthreads();
    if (tid < DEA){
      float t = 0.f;
      for (int j = tid; j < 256; j += DEA) t += sd[j];
      atomicAdd(&easum[tid], t);
    }
  }
}

// ---------- CSR scans ----------
__global__ __launch_bounds__(1024)
void k_scan1(const int* __restrict__ cnt, int* __restrict__ loc, int* __restrict__ bsum){
  __shared__ int wsum[16];
  int tid = threadIdx.x, lane = tid & 63, wv = tid >> 6;
  int i = blockIdx.x*1024 + tid;
  int v = (i < NN) ? cnt[i] : 0;
  int incl = v;
  #pragma unroll
  for (int off = 1; off < 64; off <<= 1){
    int t = __shfl_up(incl, off, 64);
    if (lane >= off) incl += t;
  }
  if (lane == 63) wsum[wv] = incl;
  __syncthreads();
  if (wv == 0){
    int s = (lane < 16) ? wsum[lane] : 0;
    #pragma unroll
    for (int off = 1; off < 16; off <<= 1){
      int t = __shfl_up(s, off, 64);
      if (lane >= off) s += t;
    }
    if (lane < 16) wsum[lane] = s;
  }
  __syncthreads();
  int excl = (wv ? wsum[wv-1] : 0) + incl - v;
  if (i < NN) loc[i] = excl;
  if (tid == 1023) bsum[blockIdx.x] = wsum[15];
}

__global__ void k_scan2(int* __restrict__ bsum, int* __restrict__ row_ptr){
  int lane = threadIdx.x;   // 64 threads
  int v = (lane < NB) ? bsum[lane] : 0;
  int incl = v;
  #pragma unroll
  for (int off = 1; off < 64; off <<= 1){
    int t = __shfl_up(incl, off, 64);
    if (lane >= off) incl += t;
  }
  if (lane < NB) bsum[lane] = incl - v;
  if (lane == 63) row_ptr[NN] = incl;
}

__global__ __launch_bounds__(1024)
void k_scan3(const int* __restrict__ loc, const int* __restrict__ bsum,
             int* __restrict__ row_ptr, int* __restrict__ wp){
  int i = blockIdx.x*1024 + threadIdx.x;
  if (i < NN){
    int v = loc[i] + bsum[blockIdx.x];
    row_ptr[i] = v; wp[i] = v;
  }
}

// ---------- k_pre2: scatter + pack W (f16 pairs) + layer-0 GraphNorm stats ----------
__global__ __launch_bounds__(256)
void k_pre2(const int* __restrict__ dst, const int* __restrict__ src,
            const float* __restrict__ ea, const float* __restrict__ easum,
            int* __restrict__ wp, int* __restrict__ csrc, uint_t* __restrict__ eas,
            const float* __restrict__ Wl, const float* __restrict__ Wr,
            uint_t* __restrict__ Wq,
            const float* __restrict__ x, const int* __restrict__ batch,
            float* __restrict__ S, float* __restrict__ Q){
  int bid = blockIdx.x;
  int tid = threadIdx.x;
  if (bid < HISTB){
    int e = bid*256 + tid;
    if (e >= ETOT) return;
    int d, s;
    if (e < EE){ d = dst[e]; s = src[e]; } else { d = e - EE; s = d; }
    int pos = atomicAdd(&wp[d], 1);
    csrc[pos] = s;
    float buf[16];
    if (e < EE){
      #pragma unroll
      for (int q = 0; q < 4; q++){
        float4 v = ld4(ea + (size_t)e*DEA + q*4);
        buf[q*4+0]=v.x; buf[q*4+1]=v.y; buf[q*4+2]=v.z; buf[q*4+3]=v.w;
      }
    } else {
      const float invE = 1.0f / (float)EE;
      #pragma unroll
      for (int k = 0; k < 16; k++) buf[k] = easum[k]*invE;
    }
    uint_t pk[8];
    #pragma unroll
    for (int p = 0; p < 8; p++)
      pk[p] = h2u(__builtin_amdgcn_cvt_pkrtz(buf[2*p], buf[2*p+1]));
    *(uint4*)(eas + (size_t)pos*8 + 0) = make_uint4(pk[0], pk[1], pk[2], pk[3]);
    *(uint4*)(eas + (size_t)pos*8 + 4) = make_uint4(pk[4], pk[5], pk[6], pk[7]);
  } else if (bid < HISTB + PACKB){
    int t = (bid - HISTB)*256 + tid;   // < 32768
    int col = t & 255;
    int kp  = (t >> 8) & 31;
    int lm  = t >> 13;                 // layer*2 + mat
    int l = lm >> 1, mat = lm & 1;
    const float* W = (mat ? Wr : Wl) + (size_t)l*CC*HC;
    float w0 = W[(size_t)(2*kp+0)*HC + col];
    float w1 = W[(size_t)(2*kp+1)*HC + col];
    Wq[(size_t)lm*8192 + kp*256 + col] = h2u(__builtin_amdgcn_cvt_pkrtz(w0, w1));
  } else {
    int c = tid & 63, g = tid >> 6;
    int r0 = (bid - HISTB - PACKB)*256;
    int hiR = r0 + 256; if (hiR > NN) hiR = NN;
    float s = 0.f, q = 0.f;
    int curb = -1;
    for (int n = r0 + g; n < hiR; n += 4){
      int b = batch[n];
      if (b != curb){
        if (curb >= 0){ atomicAdd(&S[curb*64+c], s); atomicAdd(&Q[curb*64+c], q); }
        curb = b; s = 0.f; q = 0.f;
      }
      float v = x[(size_t)n*CC + c];
      s += v; q += v*v;
    }
    if (curb >= 0){ atomicAdd(&S[curb*64+c], s); atomicAdd(&Q[curb*64+c], q); }
  }
}

// ---------- GraphNorm stats (layer 1 only) ----------
__global__ __launch_bounds__(256)
void k_stats(const float* __restrict__ x, const int* __restrict__ batch,
             float* __restrict__ S, float* __restrict__ Q){
  int c = threadIdx.x & 63, g = threadIdx.x >> 6;
  int r0 = blockIdx.x*256;
  int hiR = r0 + 256; if (hiR > NN) hiR = NN;
  float s = 0.f, q = 0.f;
  int curb = -1;
  for (int n = r0 + g; n < hiR; n += 4){
    int b = batch[n];
    if (b != curb){
      if (curb >= 0){ atomicAdd(&S[curb*64+c], s); atomicAdd(&Q[curb*64+c], q); }
      curb = b; s = 0.f; q = 0.f;
    }
    float v = x[(size_t)n*CC + c];
    s += v; q += v*v;
  }
  if (curb >= 0){ atomicAdd(&S[curb*64+c], s); atomicAdd(&Q[curb*64+c], q); }
}

__device__ __forceinline__ int lowerb(const int* a, int n, int key){
  int lo = 0, hi = n;
  while (lo < hi){ int mid = (lo+hi) >> 1; if (a[mid] < key) lo = mid+1; else hi = mid; }
  return lo;
}

// ---------- fold stats to per-(batch,channel) scale/shift ----------
__global__ void k_fin(const float* __restrict__ S, const float* __restrict__ Q,
                      const int* __restrict__ batch,
                      const float* __restrict__ w, const float* __restrict__ bb,
                      const float* __restrict__ ms,
                      float* __restrict__ scale, float* __restrict__ shift){
  __shared__ float cntf;
  int b = blockIdx.x, c = threadIdx.x;   // 64 x 64
  if (c == 0){
    int lo = lowerb(batch, NN, b), hi = lowerb(batch, NN, b+1);
    cntf = fmaxf((float)(hi - lo), 1.f);
  }
  __syncthreads();
  float inv = 1.f / cntf;
  float m = S[b*64+c] * inv;
  float a = ms[c] * m;
  float var = Q[b*64+c]*inv - 2.f*a*m + a*a;   // E[(x-a)^2]
  var = fmaxf(var, 0.f);
  float rstd = rsqrtf(var + EPSV);
  float sc = rstd * w[c];
  scale[b*64+c] = sc;
  shift[b*64+c] = bb[c] - a*sc;
}

// ---------- GEMM (f16 dot2) with fused GraphNorm+ReLU: [N,64] @ [64,256] -> bf16 ----------
__global__ __launch_bounds__(256)
void k_gemm(const float* __restrict__ x, const int* __restrict__ batch,
            const float* __restrict__ scale, const float* __restrict__ shift,
            const uint_t* __restrict__ WqA, const uint_t* __restrict__ WqB,
            ushort_t* __restrict__ outA, ushort_t* __restrict__ outB){
  const uint_t* Wq = blockIdx.z ? WqB : WqA;
  ushort_t* out = blockIdx.z ? outB : outA;
  int n0 = blockIdx.x * 64;
  __shared__ uint_t hTp[32][72];    // [kp][row] f16 pairs, 9 KB
  int tid = threadIdx.x;
  for (int t = tid; t < 1024; t += 256){      // 64 rows x 16 float4
    int r = t >> 4, ch = t & 15;
    int n = n0 + r;
    float4 v = make_float4(0.f,0.f,0.f,0.f);
    if (n < NN){
      int b = batch[n];
      v = ld4(x + (size_t)n*CC + ch*4);
      float4 sc = ld4(scale + b*64 + ch*4);
      float4 sh = ld4(shift + b*64 + ch*4);
      v.x = fmaxf(v.x*sc.x + sh.x, 0.f);
      v.y = fmaxf(v.y*sc.y + sh.y, 0.f);
      v.z = fmaxf(v.z*sc.z + sh.z, 0.f);
      v.w = fmaxf(v.w*sc.w + sh.w, 0.f);
    }
    hTp[ch*2+0][r] = h2u(__builtin_amdgcn_cvt_pkrtz(v.x, v.y));
    hTp[ch*2+1][r] = h2u(__builtin_amdgcn_cvt_pkrtz(v.z, v.w));
  }
  __syncthreads();
  int c = tid & 63, rg = tid >> 6;
  int r0 = rg * 16;
  float acc[16][4];
  #pragma unroll
  for (int i = 0; i < 16; i++){ acc[i][0]=0.f; acc[i][1]=0.f; acc[i][2]=0.f; acc[i][3]=0.f; }
  #pragma unroll 4
  for (int kp = 0; kp < 32; kp++){
    uint4 a0 = *(const uint4*)&hTp[kp][r0+0];
    uint4 a1 = *(const uint4*)&hTp[kp][r0+4];
    uint4 a2 = *(const uint4*)&hTp[kp][r0+8];
    uint4 a3 = *(const uint4*)&hTp[kp][r0+12];
    uint4 wv = *(const uint4*)(Wq + (size_t)kp*256 + c*4);
    h2t w0 = u2h(wv.x), w1 = u2h(wv.y), w2 = u2h(wv.z), w3 = u2h(wv.w);
    const uint_t av[16] = {a0.x,a0.y,a0.z,a0.w, a1.x,a1.y,a1.z,a1.w,
                           a2.x,a2.y,a2.z,a2.w, a3.x,a3.y,a3.z,a3.w};
    #pragma unroll
    for (int i = 0; i < 16; i++){
      h2t e = u2h(av[i]);
      acc[i][0] = __builtin_amdgcn_fdot2(e, w0, acc[i][0], false);
      acc[i][1] = __builtin_amdgcn_fdot2(e, w1, acc[i][1], false);
      acc[i][2] = __builtin_amdgcn_fdot2(e, w2, acc[i][2], false);
      acc[i][3] = __builtin_amdgcn_fdot2(e, w3, acc[i][3], false);
    }
  }
  #pragma unroll
  for (int i = 0; i < 16; i++){
    int n = n0 + r0 + i;
    if (n < NN){
      uint2 o;
      o.x = (uint_t)f2b(acc[i][0]) | ((uint_t)f2b(acc[i][1]) << 16);
      o.y = (uint_t)f2b(acc[i][2]) | ((uint_t)f2b(acc[i][3]) << 16);
      *(uint2*)(out + (size_t)n*HC + c*4) = o;
    }
  }
}

// ---------- FUSED GATv2: two-edge batched online softmax + 1-pair-ahead prefetch ----------
// (R16 configuration — A/B-verified best: prefetch hides the csrc->gather chain.)
__global__ __launch_bounds__(256, 4)
void k_gat(const int* __restrict__ row_ptr, const int* __restrict__ csrc,
           const uint_t* __restrict__ eas,
           const ushort_t* __restrict__ xlh, const ushort_t* __restrict__ xrh,
           const float* __restrict__ We, const float* __restrict__ att,
           const float* __restrict__ bias, const float* __restrict__ resid,
           float* __restrict__ out){
  int lane = threadIdx.x & 63;
  int h = lane >> 4, cg = lane & 15;
  int col = h*64 + cg*4;
  int wid = (blockIdx.x*256 + threadIdx.x) >> 6;
  int n0 = wid * NPW;
  if (n0 >= NN) return;
  int n1 = n0 + NPW; if (n1 > NN) n1 = NN;

  uint_t werh[4][8];
  #pragma unroll
  for (int p = 0; p < 8; p++){
    float4 w0 = ld4(We + (size_t)(2*p+0)*HC + col);
    float4 w1 = ld4(We + (size_t)(2*p+1)*HC + col);
    werh[0][p] = h2u(__builtin_amdgcn_cvt_pkrtz(w0.x, w1.x));
    werh[1][p] = h2u(__builtin_amdgcn_cvt_pkrtz(w0.y, w1.y));
    werh[2][p] = h2u(__builtin_amdgcn_cvt_pkrtz(w0.z, w1.z));
    werh[3][p] = h2u(__builtin_amdgcn_cvt_pkrtz(w0.w, w1.w));
  }
  #pragma unroll
  for (int j = 0; j < 4; j++)
    #pragma unroll
    for (int p = 0; p < 8; p++)
      asm volatile("" : "+v"(werh[j][p]));   // pin: no per-edge remat

  float4 attv = ld4(att + col);
  float4 biasv = ld4(bias + cg*4);

  for (int n = n0; n < n1; n++){
    int rr0 = rfl(row_ptr[n]), rr1 = rfl(row_ptr[n+1]);
    uint2 xrp = *(const uint2*)(xrh + (size_t)n*HC + col);
    float xr0 = b2f_lo(xrp.x), xr1 = b2f_hi(xrp.x);
    float xr2 = b2f_lo(xrp.y), xr3 = b2f_hi(xrp.y);
    float m = -3.4e38f, dsum = 0.f;
    float a0 = 0.f, a1 = 0.f, a2 = 0.f, a3 = 0.f;

    // prologue: load pair (rr0, rr0+1 clamped)
    int i1c = (rr0+1 < rr1) ? rr0+1 : rr0;
    int sA = rfl(csrc[rr0]);
    int sB = rfl(csrc[i1c]);
    uint2 xA = *(const uint2*)(xlh + (size_t)sA*HC + col);
    uint2 xB = *(const uint2*)(xlh + (size_t)sB*HC + col);
    uint_t eaA[8], eaB[8];
    {
      const uint_t* p0 = eas + (size_t)rr0*8;
      const uint_t* p1 = eas + (size_t)i1c*8;
      #pragma unroll
      for (int p = 0; p < 8; p++){ eaA[p] = p0[p]; eaB[p] = p1[p]; }
    }

    for (int idx = rr0; idx < rr1; idx += 2){
      // prefetch next pair
      int j0 = (idx+2 < rr1) ? idx+2 : rr0;
      int j1 = (idx+3 < rr1) ? idx+3 : rr0;
      int tA = rfl(csrc[j0]);
      int tB = rfl(csrc[j1]);
      uint2 xC = *(const uint2*)(xlh + (size_t)tA*HC + col);
      uint2 xD = *(const uint2*)(xlh + (size_t)tB*HC + col);
      uint_t eaC[8], eaD[8];
      {
        const uint_t* p0 = eas + (size_t)j0*8;
        const uint_t* p1 = eas + (size_t)j1*8;
        #pragma unroll
        for (int p = 0; p < 8; p++){ eaC[p] = p0[p]; eaD[p] = p1[p]; }
      }

      // unpack both xl rows
      float xl00 = b2f_lo(xA.x), xl01 = b2f_hi(xA.x);
      float xl02 = b2f_lo(xA.y), xl03 = b2f_hi(xA.y);
      float xl10 = b2f_lo(xB.x), xl11 = b2f_hi(xB.x);
      float xl12 = b2f_lo(xB.y), xl13 = b2f_hi(xB.y);

      // two independent edge-attr dots
      float p00=0.f,p01=0.f,p02=0.f,p03=0.f, p10=0.f,p11=0.f,p12=0.f,p13=0.f;
      #pragma unroll
      for (int p = 0; p < 8; p++){
        h2t e0 = u2h(eaA[p]);
        h2t e1 = u2h(eaB[p]);
        p00 = __builtin_amdgcn_fdot2(e0, u2h(werh[0][p]), p00, false);
        p10 = __builtin_amdgcn_fdot2(e1, u2h(werh[0][p]), p10, false);
        p01 = __builtin_amdgcn_fdot2(e0, u2h(werh[1][p]), p01, false);
        p11 = __builtin_amdgcn_fdot2(e1, u2h(werh[1][p]), p11, false);
        p02 = __builtin_amdgcn_fdot2(e0, u2h(werh[2][p]), p02, false);
        p12 = __builtin_amdgcn_fdot2(e1, u2h(werh[2][p]), p12, false);
        p03 = __builtin_amdgcn_fdot2(e0, u2h(werh[3][p]), p03, false);
        p13 = __builtin_amdgcn_fdot2(e1, u2h(werh[3][p]), p13, false);
      }
      float u00 = xl00 + xr0 + p00; u00 = (u00 > 0.f) ? u00 : 0.2f*u00;
      float u01 = xl01 + xr1 + p01; u01 = (u01 > 0.f) ? u01 : 0.2f*u01;
      float u02 = xl02 + xr2 + p02; u02 = (u02 > 0.f) ? u02 : 0.2f*u02;
      float u03 = xl03 + xr3 + p03; u03 = (u03 > 0.f) ? u03 : 0.2f*u03;
      float u10 = xl10 + xr0 + p10; u10 = (u10 > 0.f) ? u10 : 0.2f*u10;
      float u11 = xl11 + xr1 + p11; u11 = (u11 > 0.f) ? u11 : 0.2f*u11;
      float u12 = xl12 + xr2 + p12; u12 = (u12 > 0.f) ? u12 : 0.2f*u12;
      float u13 = xl13 + xr3 + p13; u13 = (u13 > 0.f) ? u13 : 0.2f*u13;
      float pl0 = u00*attv.x + u01*attv.y + u02*attv.z + u03*attv.w;
      float pl1 = u10*attv.x + u11*attv.y + u12*attv.z + u13*attv.w;
      pl0 = red16(pl0);
      pl1 = red16(pl1);
      if (idx + 1 >= rr1) pl1 = -3.4e38f;   // odd tail: w1 -> 0

      // combined two-edge online softmax update
      float mn = fmaxf(fmaxf(m, pl0), pl1);     // v_max3
      float sc = __expf(m - mn);
      float w0 = __expf(pl0 - mn);
      float w1 = __expf(pl1 - mn);
      dsum = dsum*sc + w0 + w1;
      a0 = a0*sc + w0*xl00 + w1*xl10;
      a1 = a1*sc + w0*xl01 + w1*xl11;
      a2 = a2*sc + w0*xl02 + w1*xl12;
      a3 = a3*sc + w0*xl03 + w1*xl13;
      m = mn;

      xA = xC; xB = xD;
      #pragma unroll
      for (int p = 0; p < 8; p++){ eaA[p] = eaC[p]; eaB[p] = eaD[p]; }
    }

    float inv = 1.0f / dsum;
    float o0 = a0*inv, o1 = a1*inv, o2 = a2*inv, o3 = a3*inv;
    #pragma unroll
    for (int off = 16; off < 64; off <<= 1){
      o0 += __shfl_xor(o0, off, 64);
      o1 += __shfl_xor(o1, off, 64);
      o2 += __shfl_xor(o2, off, 64);
      o3 += __shfl_xor(o3, off, 64);
    }
    if (lane < 16){
      float r0v = o0*0.25f + biasv.x;
      float r1v = o1*0.25f + biasv.y;
      float r2v = o2*0.25f + biasv.z;
      float r3v = o3*0.25f + biasv.w;
      if (resid){
        float4 rv = ld4(resid + (size_t)n*CC + cg*4);
        r0v += rv.x; r1v += rv.y; r2v += rv.z; r3v += rv.w;
      }
      *(float4*)(out + (size_t)n*CC + cg*4) = make_float4(r0v, r1v, r2v, r3v);
    }
  }
}

extern "C" void kernel_launch(void* const* d_in, const int* in_sizes, int n_in,
                              void* d_out, int out_size, void* d_ws, size_t ws_size,
                              hipStream_t stream) {
  const float* x     = (const float*)d_in[0];
  const int*   ei    = (const int*)d_in[1];
  const int*   src   = ei;
  const int*   dst   = ei + EE;
  const float* ea    = (const float*)d_in[2];
  const int*   batch = (const int*)d_in[3];
  const float* Wl    = (const float*)d_in[4];
  const float* Wr    = (const float*)d_in[5];
  const float* We    = (const float*)d_in[6];
  const float* att   = (const float*)d_in[7];
  const float* gb    = (const float*)d_in[8];
  const float* gw    = (const float*)d_in[9];
  const float* gnb   = (const float*)d_in[10];
  const float* gms   = (const float*)d_in[11];
  float* out = (float*)d_out;

  char* ws = (char*)d_ws;
  size_t off = 0;
  auto alloc = [&](size_t bytes) -> void* {
    void* p = ws + off; off += (bytes + 255) & ~(size_t)255; return p;
  };
  // zero-init region first (single memset covers cnt + easum + statSQ)
  int*   cnt     = (int*)alloc(NN*sizeof(int));
  float* easum   = (float*)alloc(64*sizeof(float));
  float* statSQ  = (float*)alloc(4*4096*sizeof(float));   // S0,S1,Q0,Q1
  size_t zbytes  = off;
  int*   loc     = (int*)alloc(NN*sizeof(int));
  int*   bsum    = (int*)alloc(64*sizeof(int));
  int*   wp      = (int*)alloc(NN*sizeof(int));
  int*   row_ptr = (int*)alloc((NN+1)*sizeof(int));
  int*   csrc    = (int*)alloc((size_t)ETOT*sizeof(int));
  uint_t* eas    = (uint_t*)alloc((size_t)ETOT*8*sizeof(uint_t));   // f16-packed
  float* scaleb  = (float*)alloc(4096*sizeof(float));
  float* shiftb  = (float*)alloc(4096*sizeof(float));
  uint_t* Wq     = (uint_t*)alloc((size_t)4*8192*sizeof(uint_t));   // f16-pair weights
  ushort_t* xlh  = (ushort_t*)alloc((size_t)NN*HC*sizeof(ushort_t));
  ushort_t* xrh  = (ushort_t*)alloc((size_t)NN*HC*sizeof(ushort_t));
  float* xbuf    = (float*)alloc((size_t)NN*CC*sizeof(float));
  if (off > ws_size) return;   // insufficient workspace -> fail loudly (no launch)

  hipMemsetAsync(cnt, 0, zbytes, stream);
  k_pre1<<<HISTB, 256, 0, stream>>>(ea, dst, easum, cnt);
  k_scan1<<<NB, 1024, 0, stream>>>(cnt, loc, bsum);
  k_scan2<<<1, 64, 0, stream>>>(bsum, row_ptr);
  k_scan3<<<NB, 1024, 0, stream>>>(loc, bsum, row_ptr, wp);
  k_pre2<<<HISTB + PACKB + STATB, 256, 0, stream>>>(dst, src, ea, easum, wp, csrc, eas,
                                                    Wl, Wr, Wq, x, batch,
                                                    statSQ + 0, statSQ + 2*4096);

  int gatBlocks = (NN + NPW*4 - 1) / (NPW*4);
  for (int i = 0; i < 2; i++){
    const float* xin = i ? xbuf : x;
    float* S = statSQ + i*4096;
    float* Q = statSQ + 2*4096 + i*4096;
    if (i) k_stats<<<(NN+255)/256, 256, 0, stream>>>(xin, batch, S, Q);
    k_fin<<<64, 64, 0, stream>>>(S, Q, batch, gw + i*CC, gnb + i*CC, gms + i*CC, scaleb, shiftb);
    k_gemm<<<dim3(NGB, 1, 2), 256, 0, stream>>>(xin, batch, scaleb, shiftb,
                                                Wq + (size_t)(i*2+0)*8192,
                                                Wq + (size_t)(i*2+1)*8192,
                                                xlh, xrh);
    k_gat<<<gatBlocks, 256, 0, stream>>>(row_ptr, csrc, eas, xlh, xrh,
                                         We + (size_t)i*DEA*HC, att + i*HH*CC,
                                         gb + i*CC, i ? x : nullptr, i ? out : xbuf);
  }
}